// Round 12
// baseline (804.859 us; speedup 1.0000x reference)
//
#include <hip/hip_runtime.h>

// Problem constants
constexpr int T_ = 16, B_ = 32, NI_ = 64, NO_ = 64, H_ = 256, N_ = 2048, M_ = 64, P_ = 198;
constexpr int CH_ = 8, RPC_ = N_ / CH_, NBLK_ = B_ * CH_, NTHR_ = 256;

// Tagged-payload workspace (u64 words): value in low 32, phase tag in high 32.
constexpr int OFF_G64  = 0;                      // gates  [B][1024]
constexpr int OFF_RP64 = OFF_G64 + B_ * 1024;    // rp     [B][CH][64]
constexpr int OFF_REC  = OFF_RP64 + B_ * CH_ * M_; // records[B][CH][16] (128B each)
// record idx: 0=Σes 1=es_left(s_es[1]) 2=es_right(s_es[RPC]) 3=w_left 4=w_right 5=Σwp
constexpr int WS_U64 = OFF_REC + B_ * CH_ * 16;  // 53248 u64 = 416 KB (< proven 1.08MB ws)

__device__ __forceinline__ float sigmf(float x)  { return 1.0f / (1.0f + expf(-x)); }
__device__ __forceinline__ float splusf(float x) { return fmaxf(x, 0.0f) + log1pf(expf(-fabsf(x))); }

__device__ __forceinline__ unsigned long long pk(float v, unsigned tag) {
  return ((unsigned long long)tag << 32) | (unsigned long long)__float_as_uint(v);
}
__device__ __forceinline__ float upk(unsigned long long u) {
  return __uint_as_float((unsigned)u);
}
__device__ __forceinline__ void st64(unsigned long long* p, unsigned long long v) {
  __hip_atomic_store(p, v, __ATOMIC_RELAXED, __HIP_MEMORY_SCOPE_AGENT);
}
__device__ __forceinline__ unsigned long long ld64(const unsigned long long* p) {
  return __hip_atomic_load(p, __ATOMIC_RELAXED, __HIP_MEMORY_SCOPE_AGENT);
}

__global__ void __launch_bounds__(NTHR_) ntm_kernel(
    const float* __restrict__ x,   const float* __restrict__ mem0,
    const float* __restrict__ w0,  const float* __restrict__ r0,
    const float* __restrict__ h0,  const float* __restrict__ c0,
    const float* __restrict__ Wih, const float* __restrict__ Whh,
    const float* __restrict__ bih, const float* __restrict__ bhh,
    const float* __restrict__ Wp,  const float* __restrict__ bp,
    const float* __restrict__ Wfc, const float* __restrict__ bfc,
    float* __restrict__ out, unsigned long long* __restrict__ ws)
{
  const int tid  = threadIdx.x;
  const int blk  = blockIdx.x;
  const int b    = blk >> 3;
  const int ch   = blk & 7;
  const int lane = tid & 63;
  const int wave = tid >> 6;
  const int q    = tid & 3;        // col-slice [16q,16q+16)
  const int rb   = tid >> 2;       // local row base 0..63 (rows rb+64k)
  const int n0   = ch * RPC_;

  float* membuf = out + T_ * B_ * NO_;
  unsigned long long* g64 = ws + OFF_G64  + b * 1024;
  unsigned long long* rp64= ws + OFF_RP64 + b * CH_ * M_;
  unsigned long long* rec = ws + OFF_REC  + b * CH_ * 16;

  __shared__ float s_h[H_], s_c[H_], s_r[M_], s_p[P_];
  __shared__ float s_kn[M_], s_e[M_], s_a[M_];
  __shared__ float s_es[RPC_ + 2], s_wn[RPC_ + 2], s_wpA[RPC_];
  __shared__ float s_scal[8];  // 0:beta 1:g 2..4:s 5:gamma 6:inv(Σwp) 7:invΣes & knorm via [6]? no: 6=invΣwp, knorm in 0..? use idx 7 for invΣes, knorm separate
  __shared__ float s_knorm;
  __shared__ float s_red[4];
  __shared__ float s_rp[4][M_];

  float mreg[4][16];   // mem chunk in registers

  // ---------------- init ----------------
  {
    const float* src = mem0 + ((size_t)b * N_ + n0) * M_;
    #pragma unroll
    for (int k = 0; k < 4; ++k)
      #pragma unroll
      for (int f = 0; f < 4; ++f) {
        float4 v = *(const float4*)(src + (rb + 64 * k) * M_ + q * 16 + 4 * f);
        mreg[k][4*f+0] = v.x; mreg[k][4*f+1] = v.y; mreg[k][4*f+2] = v.z; mreg[k][4*f+3] = v.w;
      }
    s_h[tid] = h0[b * H_ + tid];
    s_c[tid] = c0[b * H_ + tid];
    float v = w0[b * N_ + n0 + tid];
    #pragma unroll
    for (int o = 32; o > 0; o >>= 1) v += __shfl_xor(v, o);
    if (lane == 0) s_red[wave] = v;
    __syncthreads();
    if (tid == 0) st64(&rec[ch * 16 + 5], pk(s_red[0]+s_red[1]+s_red[2]+s_red[3], 1u));
  }

  float wp_reg = 0.f;

  for (int t = 0; ; ++t) {
    const unsigned want = (unsigned)(t + 1);
    // ===== PHASE A': poll rp+Σwp, normalize, mem-update, out, gates =====
    if (wave == 0) {
      // lanes 0..63: poll rp[c][lane] for all 8 chunks (t>0)
      if (t > 0) {
        unsigned long long v[CH_];
        unsigned sp = 0;
        for (;;) {
          bool ok = true;
          #pragma unroll
          for (int c2 = 0; c2 < CH_; ++c2) {
            v[c2] = ld64(&rp64[c2 * M_ + lane]);
            ok &= ((unsigned)(v[c2] >> 32) == want);
          }
          if (__all(ok)) break;
          __builtin_amdgcn_s_sleep(1);
          if (++sp >= (1u << 18)) break;
        }
        float racc = 0.f;
        #pragma unroll
        for (int c2 = 0; c2 < CH_; ++c2) racc += upk(v[c2]);
        s_r[lane] = racc;               // raw; scaled after sync
      } else {
        s_r[lane] = r0[b * M_ + lane];
      }
    } else if (wave == 1) {
      // lanes 0..7 poll Σwp records
      unsigned long long v = 0;
      unsigned sp = 0;
      for (;;) {
        v = (lane < CH_) ? ld64(&rec[lane * 16 + 5]) : 0;
        bool ok = (lane >= CH_) || ((unsigned)(v >> 32) == want);
        if (__all(ok)) break;
        __builtin_amdgcn_s_sleep(1);
        if (++sp >= (1u << 18)) break;
      }
      float d = (lane < CH_) ? upk(v) : 0.f;
      d += __shfl_xor(d, 1); d += __shfl_xor(d, 2); d += __shfl_xor(d, 4);
      if (lane == 0) s_scal[6] = (t == 0) ? (1.0f / d) : (1.0f / (d + 1e-12f));
    }
    __syncthreads();
    {
      float inv = s_scal[6];
      if (t > 0 && tid < M_) s_r[tid] *= inv;
      s_wn[1 + tid] = ((t == 0) ? w0[b * N_ + n0 + tid] : wp_reg) * inv;
    }
    __syncthreads();
    if (tid == 0) {
      st64(&rec[ch * 16 + 3], pk(s_wn[1],    want));
      st64(&rec[ch * 16 + 4], pk(s_wn[RPC_], want));
    }
    if (t > 0) {
      #pragma unroll
      for (int k = 0; k < 4; ++k) {
        float wn = s_wn[1 + rb + 64 * k];
        #pragma unroll
        for (int j = 0; j < 16; ++j) {
          int m = q * 16 + j;
          mreg[k][j] = mreg[k][j] * (1.0f - wn * s_e[m]) + wn * s_a[m];
        }
      }
      if (ch == 0) {
        for (int j = wave * 16; j < wave * 16 + 16; ++j) {
          float acc = 0.f;
          const float* wr = Wfc + j * (H_ + M_);
          #pragma unroll
          for (int qq = 0; qq < 4; ++qq) acc += s_h[lane + 64 * qq] * wr[lane + 64 * qq];
          acc += s_r[lane] * wr[H_ + lane];
          #pragma unroll
          for (int o = 32; o > 0; o >>= 1) acc += __shfl_xor(acc, o);
          if (lane == 0) out[(size_t)(t - 1) * B_ * NO_ + b * NO_ + j] = sigmf(acc + bfc[j]);
        }
      }
    }
    if (t == T_) break;
    {
      // gates rows [ch*128,+128): wave-coop dots; publish tagged per-row
      float hv0 = s_h[lane], hv1 = s_h[64 + lane], hv2 = s_h[128 + lane], hv3 = s_h[192 + lane];
      float rv = s_r[lane];
      float xv = x[(size_t)t * B_ * NI_ + b * NI_ + lane];
      int row0 = ch * 128 + wave * 32;
      for (int rr = 0; rr < 32; ++rr) {
        int row = row0 + rr;
        const float* wi = Wih + row * 128;
        const float* wh = Whh + row * H_;
        float acc = rv * wi[lane] + xv * wi[64 + lane]
                  + hv0 * wh[lane] + hv1 * wh[64 + lane]
                  + hv2 * wh[128 + lane] + hv3 * wh[192 + lane];
        #pragma unroll
        for (int o = 32; o > 0; o >>= 1) acc += __shfl_xor(acc, o);
        if (lane == 0) st64(&g64[row], pk(acc + bih[row] + bhh[row], want));
      }
    }
    __syncthreads();   // all waves done reading s_h/s_r before overwrite

    // ===== PHASE B: per-thread gate poll, LSTM, p, params, scores =====
    {
      const unsigned long long* gp0 = &g64[tid];
      const unsigned long long* gp1 = &g64[256 + tid];
      const unsigned long long* gp2 = &g64[512 + tid];
      const unsigned long long* gp3 = &g64[768 + tid];
      unsigned long long v0, v1, v2, v3;
      unsigned sp = 0;
      for (;;) {
        v0 = ld64(gp0); v1 = ld64(gp1); v2 = ld64(gp2); v3 = ld64(gp3);
        bool ok = ((unsigned)(v0 >> 32) == want) && ((unsigned)(v1 >> 32) == want) &&
                  ((unsigned)(v2 >> 32) == want) && ((unsigned)(v3 >> 32) == want);
        if (__all(ok)) break;
        __builtin_amdgcn_s_sleep(1);
        if (++sp >= (1u << 18)) break;
      }
      float cn = sigmf(upk(v1)) * s_c[tid] + sigmf(upk(v0)) * tanhf(upk(v2));
      float hn = sigmf(upk(v3)) * tanhf(cn);
      s_c[tid] = cn;
      s_h[tid] = hn;
    }
    __syncthreads();
    if (tid < P_) {
      float a0 = 0.f, a1 = 0.f, a2 = 0.f, a3 = 0.f;
      for (int k = 0; k < H_; k += 4) {
        a0 += s_h[k]     * Wp[k * P_ + tid];
        a1 += s_h[k + 1] * Wp[(k + 1) * P_ + tid];
        a2 += s_h[k + 2] * Wp[(k + 2) * P_ + tid];
        a3 += s_h[k + 3] * Wp[(k + 3) * P_ + tid];
      }
      s_p[tid] = bp[tid] + ((a0 + a1) + (a2 + a3));
    }
    __syncthreads();
    if (tid < M_) {
      s_kn[tid] = s_p[tid] + 1e-12f;
      s_e[tid]  = sigmf(s_p[70 + tid]);
      s_a[tid]  = tanhf(s_p[134 + tid]);
    }
    if (wave == 0) {
      float kv = s_p[lane] + 1e-12f;
      float kk = kv * kv;
      #pragma unroll
      for (int o = 32; o > 0; o >>= 1) kk += __shfl_xor(kk, o);
      if (lane == 0) s_knorm = sqrtf(kk);
    }
    if (tid == 128) {
      s_scal[0] = splusf(s_p[64]);
      s_scal[1] = sigmf(s_p[65]);
      float m3 = fmaxf(s_p[66], fmaxf(s_p[67], s_p[68]));
      float e0 = expf(s_p[66] - m3), e1 = expf(s_p[67] - m3), e2 = expf(s_p[68] - m3);
      float ss = e0 + e1 + e2;
      s_scal[2] = e0 / ss; s_scal[3] = e1 / ss; s_scal[4] = e2 / ss;
      s_scal[5] = 1.0f + splusf(s_p[69]);
    }
    __syncthreads();
    {
      const float beta = s_scal[0], knorm = s_knorm;
      float accsum = 0.f;
      #pragma unroll
      for (int k = 0; k < 4; ++k) {
        float dot = 0.f, nm = 0.f;
        #pragma unroll
        for (int j = 0; j < 16; ++j) {
          float mv = mreg[k][j] + 1e-12f;
          dot += mv * s_kn[q * 16 + j];
          nm  += mv * mv;
        }
        dot += __shfl_xor(dot, 1); dot += __shfl_xor(dot, 2);
        nm  += __shfl_xor(nm, 1);  nm  += __shfl_xor(nm, 2);
        if (q == 0) {
          float den = fmaxf(sqrtf(nm) * knorm, 1e-8f);
          float es = expf(beta * dot / den);
          s_es[1 + rb + 64 * k] = es;
          accsum += es;
        }
      }
      #pragma unroll
      for (int o = 32; o > 0; o >>= 1) accsum += __shfl_xor(accsum, o);
      if (lane == 0) s_red[wave] = accsum;
    }
    __syncthreads();
    if (tid == 0) {
      st64(&rec[ch * 16 + 0], pk(s_red[0]+s_red[1]+s_red[2]+s_red[3], want));
      st64(&rec[ch * 16 + 1], pk(s_es[1],    want));
      st64(&rec[ch * 16 + 2], pk(s_es[RPC_], want));
    }

    // ===== PHASE CD: poll Σes+halos, shift/sharpen, publish Σwp+rp =====
    if (wave == 0) {
      const int lch = (ch + 7) & 7, rch = (ch + 1) & 7;
      const unsigned long long* pp =
          (lane < 8)  ? &rec[lane * 16 + 0] :
          (lane == 8) ? &rec[lch * 16 + 2] :
          (lane == 9) ? &rec[rch * 16 + 1] :
          (lane == 10)? &rec[lch * 16 + 4] :
          (lane == 11)? &rec[rch * 16 + 3] : nullptr;
      unsigned long long v = 0;
      unsigned sp = 0;
      for (;;) {
        v = pp ? ld64(pp) : 0;
        bool ok = (!pp) || ((unsigned)(v >> 32) == want);
        if (__all(ok)) break;
        __builtin_amdgcn_s_sleep(1);
        if (++sp >= (1u << 18)) break;
      }
      if (lane == 8)  s_es[0]         = upk(v);
      if (lane == 9)  s_es[RPC_ + 1]  = upk(v);
      if (lane == 10) s_wn[0]         = upk(v);
      if (lane == 11) s_wn[RPC_ + 1]  = upk(v);
      float d = (lane < 8) ? upk(v) : 0.f;
      d += __shfl_xor(d, 1); d += __shfl_xor(d, 2); d += __shfl_xor(d, 4);
      if (lane == 0) s_scal[7] = 1.0f / d;
    }
    __syncthreads();
    {
      const float invden = s_scal[7], gG = s_scal[1];
      const float sh0 = s_scal[2], sh1 = s_scal[3], sh2 = s_scal[4], gam = s_scal[5];
      float wgm = gG * s_es[tid]     * invden + (1.0f - gG) * s_wn[tid];
      float wg0 = gG * s_es[tid + 1] * invden + (1.0f - gG) * s_wn[tid + 1];
      float wgp = gG * s_es[tid + 2] * invden + (1.0f - gG) * s_wn[tid + 2];
      float what = sh0 * wgm + sh1 * wg0 + sh2 * wgp;
      wp_reg = expf(gam * logf(what));
      s_wpA[tid] = wp_reg;
      float acc = wp_reg;
      #pragma unroll
      for (int o = 32; o > 0; o >>= 1) acc += __shfl_xor(acc, o);
      if (lane == 0) s_red[wave] = acc;
    }
    __syncthreads();
    if (tid == 0) st64(&rec[ch * 16 + 5], pk(s_red[0]+s_red[1]+s_red[2]+s_red[3], want + 1));
    {
      float v[16];
      #pragma unroll
      for (int j = 0; j < 16; ++j) v[j] = 0.f;
      #pragma unroll
      for (int k = 0; k < 4; ++k) {
        float wp = s_wpA[rb + 64 * k];
        #pragma unroll
        for (int j = 0; j < 16; ++j) v[j] += wp * mreg[k][j];
      }
      #pragma unroll
      for (int a = 0; a < 4; ++a) {
        const int bit = 2 + a;
        int myb = (lane >> bit) & 1;
        const int L = 16 >> (a + 1);
        float nv[8];
        #pragma unroll
        for (int j2 = 0; j2 < L; ++j2) {
          float keep = myb ? v[2 * j2 + 1] : v[2 * j2];
          float send = myb ? v[2 * j2]     : v[2 * j2 + 1];
          float got  = __shfl_xor(send, 1 << bit);
          nv[j2] = keep + got;
        }
        #pragma unroll
        for (int j2 = 0; j2 < L; ++j2) v[j2] = nv[j2];
      }
      s_rp[wave][16 * (lane & 3) + (lane >> 2)] = v[0];
    }
    __syncthreads();
    if (tid < M_) {
      float rv = s_rp[0][tid] + s_rp[1][tid] + s_rp[2][tid] + s_rp[3][tid];
      st64(&rp64[ch * M_ + tid], pk(rv, want + 1));
    }
  }

  // ---------------- final: store mem registers to d_out tail ----------------
  {
    float* dst = membuf + ((size_t)b * N_ + n0) * M_;
    #pragma unroll
    for (int k = 0; k < 4; ++k)
      #pragma unroll
      for (int f = 0; f < 4; ++f) {
        float4 vv = make_float4(mreg[k][4*f], mreg[k][4*f+1], mreg[k][4*f+2], mreg[k][4*f+3]);
        *(float4*)(dst + (rb + 64 * k) * M_ + q * 16 + 4 * f) = vv;
      }
  }
}

extern "C" void kernel_launch(void* const* d_in, const int* in_sizes, int n_in,
                              void* d_out, int out_size, void* d_ws, size_t ws_size,
                              hipStream_t stream) {
  const float* x   = (const float*)d_in[0];
  const float* mem = (const float*)d_in[1];
  const float* w0  = (const float*)d_in[2];
  const float* r0  = (const float*)d_in[3];
  const float* h0  = (const float*)d_in[4];
  const float* c0  = (const float*)d_in[5];
  const float* Wih = (const float*)d_in[6];
  const float* Whh = (const float*)d_in[7];
  const float* bih = (const float*)d_in[8];
  const float* bhh = (const float*)d_in[9];
  const float* Wp  = (const float*)d_in[10];
  const float* bp  = (const float*)d_in[11];
  const float* Wfc = (const float*)d_in[12];
  const float* bfc = (const float*)d_in[13];
  float* out = (float*)d_out;
  unsigned long long* wsp = (unsigned long long*)d_ws;
  // No memset needed: 0xAA poison = tag 0xAAAAAAAA, matches no phase tag (1..18).
  hipLaunchKernelGGL(ntm_kernel, dim3(NBLK_), dim3(NTHR_), 0, stream,
                     x, mem, w0, r0, h0, c0, Wih, Whh, bih, bhh,
                     Wp, bp, Wfc, bfc, out, wsp);
}